// Round 1
// 1731.968 us; speedup vs baseline: 1.3462x; 1.3462x over previous
//
#include <hip/hip_runtime.h>
#include <hip/hip_bf16.h>
#include <stdint.h>

// Problem: out[n,o] = sum_i x[n,i] * w_dq[o,i] + bias[o]
//   x: [8192, 4096] f32, weight: [16384, 4096] f32, bias: [16384] f32
//   w_dq = clip(round(w/scale), -8, 7) * scale, scale = max(max|w|/7, 1e-8)
#define M_DIM 8192
#define K_DIM 4096
#define N_DIM 16384

// 256^2 8-phase template (m201): BM=BN=256, BK=64, 8 waves (2Mx4N), 128 KiB LDS
#define BM 256
#define BN 256
#define BK 64
#define NIT (K_DIM / (2 * BK))   // 32 iterations, 2 K-tiles each

typedef __attribute__((ext_vector_type(8))) short    short8;   // 8 bf16 (4 VGPRs) MFMA A/B frag
typedef __attribute__((ext_vector_type(4))) float    f32x4;    // MFMA C/D frag
typedef __attribute__((ext_vector_type(8))) unsigned short ushort8;

// f32 -> bf16, round-to-nearest-even (finite inputs only)
__device__ inline unsigned short f2bf(float f) {
    unsigned u = __float_as_uint(f);
    u = (u + 0x7fffu + ((u >> 16) & 1u)) >> 16;
    return (unsigned short)u;
}

// ---------------- kernel 1: max|w| reduction ----------------
__global__ void absmax_kernel(const float* __restrict__ w, unsigned* __restrict__ out, int n4) {
    int tid = blockIdx.x * blockDim.x + threadIdx.x;
    int stride = gridDim.x * blockDim.x;
    float m = 0.0f;
    for (int i = tid; i < n4; i += stride) {
        float4 v = ((const float4*)w)[i];
        m = fmaxf(m, fmaxf(fmaxf(fabsf(v.x), fabsf(v.y)), fmaxf(fabsf(v.z), fabsf(v.w))));
    }
    #pragma unroll
    for (int off = 32; off > 0; off >>= 1)
        m = fmaxf(m, __shfl_down(m, off, 64));
    __shared__ float smax[4];
    int lane = threadIdx.x & 63, wv = threadIdx.x >> 6;
    if (lane == 0) smax[wv] = m;
    __syncthreads();
    if (threadIdx.x == 0) {
        float b = fmaxf(fmaxf(smax[0], smax[1]), fmaxf(smax[2], smax[3]));
        atomicMax(out, __float_as_uint(b));   // all values >= 0: IEEE bits order as uints
    }
}

// ---------------- kernel 2: quantize+dequant weight -> bf16 ----------------
__global__ void quant_w_kernel(const float* __restrict__ w, const unsigned* __restrict__ maxbits,
                               unsigned short* __restrict__ wq, int n8) {
    float scale = fmaxf(__uint_as_float(*maxbits) / 7.0f, 1e-8f);
    int tid = blockIdx.x * blockDim.x + threadIdx.x;
    int stride = gridDim.x * blockDim.x;
    for (int i = tid; i < n8; i += stride) {
        float4 a = ((const float4*)w)[2 * i];
        float4 b = ((const float4*)w)[2 * i + 1];
        float v[8] = {a.x, a.y, a.z, a.w, b.x, b.y, b.z, b.w};
        ushort8 o;
        #pragma unroll
        for (int j = 0; j < 8; j++) {
            // true division + rintf => bit-exact match with numpy round-half-even
            float q = rintf(v[j] / scale);
            q = fminf(fmaxf(q, -8.0f), 7.0f);
            o[j] = f2bf(q * scale);
        }
        ((ushort8*)wq)[i] = o;
    }
}

// ---------------- kernel 3: x f32 -> bf16 ----------------
__global__ void cvt_x_kernel(const float* __restrict__ x, unsigned short* __restrict__ xb, int n8) {
    int tid = blockIdx.x * blockDim.x + threadIdx.x;
    int stride = gridDim.x * blockDim.x;
    for (int i = tid; i < n8; i += stride) {
        float4 a = ((const float4*)x)[2 * i];
        float4 b = ((const float4*)x)[2 * i + 1];
        ushort8 o;
        o[0] = f2bf(a.x); o[1] = f2bf(a.y); o[2] = f2bf(a.z); o[3] = f2bf(a.w);
        o[4] = f2bf(b.x); o[5] = f2bf(b.y); o[6] = f2bf(b.z); o[7] = f2bf(b.w);
        ((ushort8*)xb)[i] = o;
    }
}

// ---------------- kernel 4: bf16 GEMM (B^T input) + bias, f32 out ----------------
// 256x256 tile, BK=64, 512 threads (8 waves, 2Mx4N), double-buffered 128 KiB LDS,
// 8-phase schedule with counted vmcnt(6) (T3+T4), LDS XOR-swizzle via pre-swizzled
// global source (T2, rule #21), s_setprio around MFMA clusters (T5),
// bijective XCD-aware blockIdx swizzle (T1).
//
// LDS map (ushort idx): A[buf] at buf*16384, B[buf] at 32768 + buf*16384.
// Tile layout [256 rows][64 cols]; half h = rows h*128..h*128+127 (8192 ushorts).
// Swizzle: physical 16B-chunk p of row r holds logical chunk p ^ (r&7).
//
// Schedule ledger (iteration computes K-tiles 2it->buf0, 2it+1->buf1):
//   reads:  P1: A(mi0-3)+B(all) of buf0   P3: A(mi4-7) of buf0
//           P5: A(mi0-3)+B(all) of buf1   P7: A(mi4-7) of buf1
//   MFMA:   P1 (A0,B0) P2 (A0,B1) P3 (A1,B1) P4 (A1,B0)  [x2 kk each = 16/phase]
//   stages: P1: K(2it+1) A-h1 | P2..P5: K(2it+2) Bh0,Bh1,Ah0,Ah1
//           P6..P8: K(2it+3) Bh0,Bh1,Ah0   (each stage issued only after the
//           barrier retiring the last read of the half it overwrites)
//   waits:  vmcnt(6) after stage at P4 and P8 -> drains the 4 half-tiles the next
//           read phase needs, leaves 3 half-tiles in flight.
__global__ __launch_bounds__(512, 2)
void gemm_bt_bias(const unsigned short* __restrict__ A,
                  const unsigned short* __restrict__ B,
                  const float* __restrict__ bias,
                  float* __restrict__ C) {
    __shared__ __align__(16) unsigned short lds[65536];   // 128 KiB

    const int tid  = threadIdx.x;
    const int lane = tid & 63;
    const int wid  = tid >> 6;          // 0..7
    const int wr   = wid >> 2;          // 0..1 -> 128 output rows
    const int wc   = wid & 3;           // 0..3 -> 64 output cols
    const int l15  = lane & 15;
    const int quad = lane >> 4;
    const int sx   = l15 & 7;           // read-side swizzle key (tile-row & 7)

    // T1: bijective XCD swizzle. 2048 wgs, 2048 % 8 == 0 -> simple form.
    const int swz = (blockIdx.x & 7) * (2048 / 8) + (blockIdx.x >> 3);
    const int bx  = swz & 63;           // N-tile (fast) -> consecutive swz share A panel
    const int by  = swz >> 6;           // M-tile
    const long arow0 = (long)by * BM;
    const long brow0 = (long)bx * BN;

    // Staging constants: thread covers 16B chunk c0=tid and c1=512+tid of each half-tile.
    // row r = c>>3 (c1: r0+64, same r&7), logical col chunk = (tid&7) ^ (r&7) (inverse swizzle).
    const int r0   = tid >> 3;                         // 0..63
    const int colE = ((tid & 7) ^ (r0 & 7)) * 8;       // element col within 64-col K-window
    const unsigned short* aSrc = A + (arow0 + r0) * (long)K_DIM + colE;
    const unsigned short* bSrc = B + (brow0 + r0) * (long)K_DIM + colE;
    unsigned short* ldst = lds + tid * 8;

    // ds_read element offsets (swizzled): row*64 + ((kk*4+quad)^sx)*8
    int aOff[2], bOff[2];
    #pragma unroll
    for (int kk = 0; kk < 2; ++kk) {
        const int ck = (((kk * 4 + quad) ^ sx)) * 8;
        aOff[kk] = (wr * 128 + l15) * 64 + ck;
        bOff[kk] = 32768 + (wc * 64 + l15) * 64 + ck;
    }

#define STG_A(kt, h) do {                                                             \
    const unsigned short* _s = aSrc + (size_t)(h) * (128 * K_DIM) + (size_t)(kt) * BK; \
    unsigned short* _d = ldst + ((kt) & 1) * 16384 + (h) * 8192;                       \
    __builtin_amdgcn_global_load_lds((const __attribute__((address_space(1))) void*)_s,\
        (__attribute__((address_space(3))) void*)_d, 16, 0, 0);                        \
    __builtin_amdgcn_global_load_lds((const __attribute__((address_space(1))) void*)(_s + 64 * K_DIM), \
        (__attribute__((address_space(3))) void*)(_d + 4096), 16, 0, 0);               \
} while (0)

#define STG_B(kt, h) do {                                                             \
    const unsigned short* _s = bSrc + (size_t)(h) * (128 * K_DIM) + (size_t)(kt) * BK; \
    unsigned short* _d = ldst + 32768 + ((kt) & 1) * 16384 + (h) * 8192;               \
    __builtin_amdgcn_global_load_lds((const __attribute__((address_space(1))) void*)_s,\
        (__attribute__((address_space(3))) void*)_d, 16, 0, 0);                        \
    __builtin_amdgcn_global_load_lds((const __attribute__((address_space(1))) void*)(_s + 64 * K_DIM), \
        (__attribute__((address_space(3))) void*)(_d + 4096), 16, 0, 0);               \
} while (0)

#define LDA(af, buf, mb) do {                                                         \
    _Pragma("unroll") for (int _mi = 0; _mi < 4; ++_mi)                               \
    _Pragma("unroll") for (int _kk = 0; _kk < 2; ++_kk)                               \
        af[_mi][_kk] = *(const short8*)(lds + (buf) * 16384 + aOff[_kk] + ((mb) + _mi) * 1024); \
} while (0)

#define LDB(buf) do {                                                                 \
    _Pragma("unroll") for (int _ni = 0; _ni < 4; ++_ni)                               \
    _Pragma("unroll") for (int _kk = 0; _kk < 2; ++_kk)                               \
        bf[_ni][_kk] = *(const short8*)(lds + (buf) * 16384 + bOff[_kk] + _ni * 1024); \
} while (0)

#define MMA(af, mb, nb) do {                                                          \
    __builtin_amdgcn_s_setprio(1);                                                    \
    _Pragma("unroll") for (int _mi = 0; _mi < 4; ++_mi)                               \
    _Pragma("unroll") for (int _nj = 0; _nj < 2; ++_nj)                               \
    _Pragma("unroll") for (int _kk = 0; _kk < 2; ++_kk)                               \
        acc[(mb) + _mi][(nb) + _nj] = __builtin_amdgcn_mfma_f32_16x16x32_bf16(         \
            af[_mi][_kk], bf[(nb) + _nj][_kk], acc[(mb) + _mi][(nb) + _nj], 0, 0, 0);  \
    __builtin_amdgcn_s_setprio(0);                                                    \
} while (0)

#define BARR() __builtin_amdgcn_s_barrier()
#define LG0()  asm volatile("s_waitcnt lgkmcnt(0)" ::: "memory")
#define VM6()  asm volatile("s_waitcnt vmcnt(6)" ::: "memory")
#define VM4()  asm volatile("s_waitcnt vmcnt(4)" ::: "memory")
#define VM0()  asm volatile("s_waitcnt vmcnt(0)" ::: "memory")

    f32x4 acc[8][4];
    #pragma unroll
    for (int mi = 0; mi < 8; ++mi)
        #pragma unroll
        for (int ni = 0; ni < 4; ++ni)
            acc[mi][ni] = 0.0f;

    short8 afA[4][2], afB[4][2], bf[4][2];

    // ---- prologue: K0 (4 halves) + K1 (3 halves); K1's A-h1 arrives at loop P1
    STG_B(0, 0); STG_B(0, 1); STG_A(0, 0); STG_A(0, 1);
    VM4();
    STG_B(1, 0); STG_B(1, 1); STG_A(1, 0);
    VM6();
    BARR();

    // ---- steady loop: all stage targets valid through it=30 (max kt = 63)
    for (int it = 0; it < NIT - 1; ++it) {
        // P1
        LDA(afA, 0, 0); LDB(0); STG_A(2 * it + 1, 1);
        BARR(); LG0(); MMA(afA, 0, 0); BARR();
        // P2
        STG_B(2 * it + 2, 0);
        BARR(); LG0(); MMA(afA, 0, 2); BARR();
        // P3
        LDA(afB, 0, 4); STG_B(2 * it + 2, 1);
        BARR(); LG0(); MMA(afB, 4, 2); BARR();
        // P4
        STG_A(2 * it + 2, 0); VM6();
        BARR(); LG0(); MMA(afB, 4, 0); BARR();
        // P5
        LDA(afA, 1, 0); LDB(1); STG_A(2 * it + 2, 1);
        BARR(); LG0(); MMA(afA, 0, 0); BARR();
        // P6
        STG_B(2 * it + 3, 0);
        BARR(); LG0(); MMA(afA, 0, 2); BARR();
        // P7
        LDA(afB, 1, 4); STG_B(2 * it + 3, 1);
        BARR(); LG0(); MMA(afB, 4, 2); BARR();
        // P8
        STG_A(2 * it + 3, 0); VM6();
        BARR(); LG0(); MMA(afB, 4, 0); BARR();
    }

    // ---- peeled last iteration (K62/K63): no new stages except K63 A-h1; drain at P4
    LDA(afA, 0, 0); LDB(0); STG_A(2 * (NIT - 1) + 1, 1);
    BARR(); LG0(); MMA(afA, 0, 0); BARR();
    BARR(); LG0(); MMA(afA, 0, 2); BARR();
    LDA(afB, 0, 4);
    BARR(); LG0(); MMA(afB, 4, 2); BARR();
    VM0();
    BARR(); LG0(); MMA(afB, 4, 0); BARR();
    LDA(afA, 1, 0); LDB(1);
    BARR(); LG0(); MMA(afA, 0, 0); BARR();
    BARR(); LG0(); MMA(afA, 0, 2); BARR();
    LDA(afB, 1, 4);
    BARR(); LG0(); MMA(afB, 4, 2); BARR();
    BARR(); LG0(); MMA(afB, 4, 0);

    // ---- epilogue: C/D layout col=lane&15, row=quad*4+reg
    const long crow0 = arow0 + wr * 128;
    const long ccol0 = brow0 + wc * 64;
    #pragma unroll
    for (int ni = 0; ni < 4; ++ni) {
        const long col = ccol0 + ni * 16 + l15;
        const float bv = bias[col];
        #pragma unroll
        for (int mi = 0; mi < 8; ++mi) {
            #pragma unroll
            for (int v = 0; v < 4; ++v) {
                const long row = crow0 + mi * 16 + quad * 4 + v;
                C[row * N_DIM + col] = acc[mi][ni][v] + bv;
            }
        }
    }
#undef STG_A
#undef STG_B
#undef LDA
#undef LDB
#undef MMA
#undef BARR
#undef LG0
#undef VM6
#undef VM4
#undef VM0
}

extern "C" void kernel_launch(void* const* d_in, const int* in_sizes, int n_in,
                              void* d_out, int out_size, void* d_ws, size_t ws_size,
                              hipStream_t stream) {
    const float* x    = (const float*)d_in[0];   // [8192, 4096]
    const float* w    = (const float*)d_in[1];   // [16384, 4096]
    const float* bias = (const float*)d_in[2];   // [16384]
    float* out        = (float*)d_out;           // [8192, 16384]

    // workspace layout: [0,4) max|w| bits; +256: x_bf16 (64 MiB); then w_bf16 (128 MiB)
    unsigned* maxbits  = (unsigned*)d_ws;
    unsigned short* xb = (unsigned short*)((char*)d_ws + 256);
    unsigned short* wb = (unsigned short*)((char*)d_ws + 256 + (size_t)M_DIM * K_DIM * 2);

    hipMemsetAsync(d_ws, 0, 4, stream);  // zero the atomicMax slot (ws is poisoned 0xAA)

    absmax_kernel<<<4096, 256, 0, stream>>>(w, maxbits, (N_DIM * K_DIM) / 4);
    quant_w_kernel<<<4096, 256, 0, stream>>>(w, maxbits, wb, (N_DIM * K_DIM) / 8);
    cvt_x_kernel<<<4096, 256, 0, stream>>>(x, xb, (M_DIM * K_DIM) / 8);

    // 2048 one-dimensional workgroups; tile mapping + XCD swizzle inside the kernel
    gemm_bt_bias<<<dim3(2048), 512, 0, stream>>>(xb, wb, bias, out);
}